// Round 1
// baseline (906.470 us; speedup 1.0000x reference)
//
#include <hip/hip_runtime.h>
#include <math.h>

// TCN: B=16, S=4096, Cin0=64, C=128, K=2, 5 levels, dilations 1,2,4,8,16.
// Final output = level4_out + level0_out (skip).
// All fp32. Round 0: correctness-first tiled vector-FMA kernels.

#define S_LEN 4096
#define COUT 128
#define S_TILE 128
#define XSTR 144   // 128 + max halo (d=16)

__device__ __forceinline__ float elu_f(float v) {
    return v > 0.0f ? v : (__expf(v) - 1.0f);
}

// ---------------------------------------------------------------------------
// K=2 dilated causal conv + bias + ELU.  out = elu(conv(x) + b)
// Cin in {64,128}, Cout=128.  Grid: (S/128, B). Block: 256.
// ---------------------------------------------------------------------------
__global__ __launch_bounds__(256)
void conv_k2_elu(const float* __restrict__ x, const float* __restrict__ w,
                 const float* __restrict__ bias, float* __restrict__ out,
                 int Cin, int d)
{
    __shared__ float Xls[8 * XSTR];
    __shared__ float Wls[16 * COUT];   // [ci_local*2 + k][co]
    __shared__ float Bls[COUT];

    const int tid = threadIdx.x;
    const int sg  = tid & 15;          // s lane (stride-16 blocking)
    const int cg  = tid >> 4;          // 16 co-groups of 8
    const int s0  = blockIdx.x * S_TILE;
    const int b   = blockIdx.y;
    const int co8 = cg * 8;

    if (tid < COUT) Bls[tid] = bias[tid];

    float acc[8][8];
    #pragma unroll
    for (int j = 0; j < 8; ++j)
        #pragma unroll
        for (int u = 0; u < 8; ++u) acc[j][u] = 0.0f;

    const int rowlen = S_TILE + d;
    const int lane32 = tid & 31;
    const int rrow   = tid >> 5;       // 0..7 staging row

    for (int c0 = 0; c0 < Cin; c0 += 8) {
        // ---- stage X rows [c0+rrow][s0-d .. s0+127]
        {
            const float* xp = x + ((size_t)(b * Cin + c0 + rrow)) * S_LEN;
            float* xs = Xls + rrow * XSTR;
            for (int i = lane32; i < rowlen; i += 32) {
                int gs = s0 - d + i;
                float v = 0.0f;
                if (gs >= 0) v = xp[gs];
                xs[i] = v;
            }
        }
        // ---- stage W: 8 ci x 128 co x 2 k = 512 float4 (16 contiguous floats/co)
        {
            #pragma unroll
            for (int rep = 0; rep < 2; ++rep) {
                int f  = tid + rep * 256;
                int co = f >> 2, q = f & 3;
                const float4 v = *(const float4*)(w + ((size_t)(co * Cin + c0)) * 2 + q * 4);
                float* dst = Wls + (q * 4) * COUT + co;   // rows e = q*4+j, e = ci_local*2+k
                dst[0 * COUT] = v.x; dst[1 * COUT] = v.y;
                dst[2 * COUT] = v.z; dst[3 * COUT] = v.w;
            }
        }
        __syncthreads();

        #pragma unroll
        for (int ci = 0; ci < 8; ++ci) {
            const float* Xrow = Xls + ci * XSTR;
            float xa[8], xb[8];
            #pragma unroll
            for (int u = 0; u < 8; ++u) {
                xa[u] = Xrow[sg + 16 * u];        // x[s-d]
                xb[u] = Xrow[sg + 16 * u + d];    // x[s]
            }
            const float4 w0a = *(const float4*)&Wls[(ci * 2 + 0) * COUT + co8];
            const float4 w0b = *(const float4*)&Wls[(ci * 2 + 0) * COUT + co8 + 4];
            const float4 w1a = *(const float4*)&Wls[(ci * 2 + 1) * COUT + co8];
            const float4 w1b = *(const float4*)&Wls[(ci * 2 + 1) * COUT + co8 + 4];
            const float w0[8] = {w0a.x, w0a.y, w0a.z, w0a.w, w0b.x, w0b.y, w0b.z, w0b.w};
            const float w1[8] = {w1a.x, w1a.y, w1a.z, w1a.w, w1b.x, w1b.y, w1b.z, w1b.w};
            #pragma unroll
            for (int j = 0; j < 8; ++j)
                #pragma unroll
                for (int u = 0; u < 8; ++u)
                    acc[j][u] = fmaf(w0[j], xa[u], fmaf(w1[j], xb[u], acc[j][u]));
        }
        __syncthreads();
    }

    #pragma unroll
    for (int j = 0; j < 8; ++j) {
        const int co = co8 + j;
        const float bb = Bls[co];
        float* op = out + ((size_t)(b * COUT + co)) * S_LEN + s0 + sg;
        #pragma unroll
        for (int u = 0; u < 8; ++u)
            op[16 * u] = elu_f(acc[j][u] + bb);
    }
}

// ---------------------------------------------------------------------------
// K=2 conv + bias + ELU, then + residual, ELU, optional + skip.
// out = elu( elu(conv(t)+b) + res ) [+ skip]
// Cin = 128 fixed. Grid: (S/128, B). Block: 256.
// ---------------------------------------------------------------------------
__global__ __launch_bounds__(256)
void conv_k2_res(const float* __restrict__ x, const float* __restrict__ w,
                 const float* __restrict__ bias, const float* __restrict__ res,
                 const float* __restrict__ skip, float* __restrict__ out, int d)
{
    __shared__ float Xls[8 * XSTR];
    __shared__ float Wls[16 * COUT];
    __shared__ float Bls[COUT];

    const int Cin = COUT;
    const int tid = threadIdx.x;
    const int sg  = tid & 15;
    const int cg  = tid >> 4;
    const int s0  = blockIdx.x * S_TILE;
    const int b   = blockIdx.y;
    const int co8 = cg * 8;

    if (tid < COUT) Bls[tid] = bias[tid];

    float acc[8][8];
    #pragma unroll
    for (int j = 0; j < 8; ++j)
        #pragma unroll
        for (int u = 0; u < 8; ++u) acc[j][u] = 0.0f;

    const int rowlen = S_TILE + d;
    const int lane32 = tid & 31;
    const int rrow   = tid >> 5;

    for (int c0 = 0; c0 < Cin; c0 += 8) {
        {
            const float* xp = x + ((size_t)(b * Cin + c0 + rrow)) * S_LEN;
            float* xs = Xls + rrow * XSTR;
            for (int i = lane32; i < rowlen; i += 32) {
                int gs = s0 - d + i;
                float v = 0.0f;
                if (gs >= 0) v = xp[gs];
                xs[i] = v;
            }
        }
        {
            #pragma unroll
            for (int rep = 0; rep < 2; ++rep) {
                int f  = tid + rep * 256;
                int co = f >> 2, q = f & 3;
                const float4 v = *(const float4*)(w + ((size_t)(co * Cin + c0)) * 2 + q * 4);
                float* dst = Wls + (q * 4) * COUT + co;
                dst[0 * COUT] = v.x; dst[1 * COUT] = v.y;
                dst[2 * COUT] = v.z; dst[3 * COUT] = v.w;
            }
        }
        __syncthreads();

        #pragma unroll
        for (int ci = 0; ci < 8; ++ci) {
            const float* Xrow = Xls + ci * XSTR;
            float xa[8], xb[8];
            #pragma unroll
            for (int u = 0; u < 8; ++u) {
                xa[u] = Xrow[sg + 16 * u];
                xb[u] = Xrow[sg + 16 * u + d];
            }
            const float4 w0a = *(const float4*)&Wls[(ci * 2 + 0) * COUT + co8];
            const float4 w0b = *(const float4*)&Wls[(ci * 2 + 0) * COUT + co8 + 4];
            const float4 w1a = *(const float4*)&Wls[(ci * 2 + 1) * COUT + co8];
            const float4 w1b = *(const float4*)&Wls[(ci * 2 + 1) * COUT + co8 + 4];
            const float w0[8] = {w0a.x, w0a.y, w0a.z, w0a.w, w0b.x, w0b.y, w0b.z, w0b.w};
            const float w1[8] = {w1a.x, w1a.y, w1a.z, w1a.w, w1b.x, w1b.y, w1b.z, w1b.w};
            #pragma unroll
            for (int j = 0; j < 8; ++j)
                #pragma unroll
                for (int u = 0; u < 8; ++u)
                    acc[j][u] = fmaf(w0[j], xa[u], fmaf(w1[j], xb[u], acc[j][u]));
        }
        __syncthreads();
    }

    const bool has_skip = (skip != nullptr);
    #pragma unroll
    for (int j = 0; j < 8; ++j) {
        const int co = co8 + j;
        const float bb = Bls[co];
        const size_t rowoff = ((size_t)(b * COUT + co)) * S_LEN + s0 + sg;
        const float* rp = res + rowoff;
        float* op = out + rowoff;
        #pragma unroll
        for (int u = 0; u < 8; ++u) {
            float y = elu_f(elu_f(acc[j][u] + bb) + rp[16 * u]);
            if (has_skip) y += skip[rowoff + 16 * u];
            op[16 * u] = y;
        }
    }
}

// ---------------------------------------------------------------------------
// 1x1 conv + bias (no ELU): downsample residual for level 0.
// Cin=64, Cout=128. Grid: (S/128, B). Block: 256.
// ---------------------------------------------------------------------------
__global__ __launch_bounds__(256)
void conv_k1(const float* __restrict__ x, const float* __restrict__ w,
             const float* __restrict__ bias, float* __restrict__ out, int Cin)
{
    __shared__ float Xls[8 * S_TILE];
    __shared__ float Wls[8 * COUT];
    __shared__ float Bls[COUT];

    const int tid = threadIdx.x;
    const int sg  = tid & 15;
    const int cg  = tid >> 4;
    const int s0  = blockIdx.x * S_TILE;
    const int b   = blockIdx.y;
    const int co8 = cg * 8;

    if (tid < COUT) Bls[tid] = bias[tid];

    float acc[8][8];
    #pragma unroll
    for (int j = 0; j < 8; ++j)
        #pragma unroll
        for (int u = 0; u < 8; ++u) acc[j][u] = 0.0f;

    const int lane32 = tid & 31;
    const int rrow   = tid >> 5;

    for (int c0 = 0; c0 < Cin; c0 += 8) {
        {
            const float* xp = x + ((size_t)(b * Cin + c0 + rrow)) * S_LEN + s0;
            float* xs = Xls + rrow * S_TILE;
            #pragma unroll
            for (int i = lane32; i < S_TILE; i += 32) xs[i] = xp[i];
        }
        {
            // 8 ci x 128 co = 256 float4 (8 contiguous floats per co)
            int f  = tid;
            int co = f >> 1, q = f & 1;
            const float4 v = *(const float4*)(w + (size_t)co * Cin + c0 + q * 4);
            float* dst = Wls + (q * 4) * COUT + co;
            dst[0 * COUT] = v.x; dst[1 * COUT] = v.y;
            dst[2 * COUT] = v.z; dst[3 * COUT] = v.w;
        }
        __syncthreads();

        #pragma unroll
        for (int ci = 0; ci < 8; ++ci) {
            const float* Xrow = Xls + ci * S_TILE;
            float xa[8];
            #pragma unroll
            for (int u = 0; u < 8; ++u) xa[u] = Xrow[sg + 16 * u];
            const float4 wa = *(const float4*)&Wls[ci * COUT + co8];
            const float4 wb = *(const float4*)&Wls[ci * COUT + co8 + 4];
            const float w0[8] = {wa.x, wa.y, wa.z, wa.w, wb.x, wb.y, wb.z, wb.w};
            #pragma unroll
            for (int j = 0; j < 8; ++j)
                #pragma unroll
                for (int u = 0; u < 8; ++u)
                    acc[j][u] = fmaf(w0[j], xa[u], acc[j][u]);
        }
        __syncthreads();
    }

    #pragma unroll
    for (int j = 0; j < 8; ++j) {
        const int co = co8 + j;
        const float bb = Bls[co];
        float* op = out + ((size_t)(b * COUT + co)) * S_LEN + s0 + sg;
        #pragma unroll
        for (int u = 0; u < 8; ++u)
            op[16 * u] = acc[j][u] + bb;   // no ELU on downsample
    }
}

// ---------------------------------------------------------------------------
extern "C" void kernel_launch(void* const* d_in, const int* in_sizes, int n_in,
                              void* d_out, int out_size, void* d_ws, size_t ws_size,
                              hipStream_t stream) {
    const float* x_in = (const float*)d_in[0];   // [16,64,4096]
    const float* w1_0 = (const float*)d_in[1];   // [128,64,2]
    const float* b1_0 = (const float*)d_in[2];   // [128]
    const float* w2_0 = (const float*)d_in[3];   // [128,128,2]
    const float* b2_0 = (const float*)d_in[4];   // [128]
    const float* ds_w = (const float*)d_in[5];   // [128,64,1]
    const float* ds_b = (const float*)d_in[6];   // [128]
    const float* W1   = (const float*)d_in[7];   // [4,128,128,2]
    const float* B1   = (const float*)d_in[8];   // [4,128]
    const float* W2   = (const float*)d_in[9];   // [4,128,128,2]
    const float* B2   = (const float*)d_in[10];  // [4,128]
    float* out = (float*)d_out;                  // [16,128,4096]

    const size_t N = (size_t)16 * 128 * 4096;    // 8,388,608 floats per tensor
    float* t    = (float*)d_ws;                  // conv1 output scratch
    float* x1   = t + N;                         // level-0 output (kept for final skip)
    float* bufA = x1 + N;                        // ping buffer (pong = d_out)

    const size_t Wsz = (size_t)128 * 128 * 2;    // per-level weight stride
    dim3 grid(S_LEN / S_TILE, 16);               // (32, 16)
    dim3 block(256);

    // ---- Level 0 (d=1, 64->128 ch, downsample residual)
    conv_k2_elu<<<grid, block, 0, stream>>>(x_in, w1_0, b1_0, t, 64, 1);
    conv_k1   <<<grid, block, 0, stream>>>(x_in, ds_w, ds_b, bufA, 64);
    conv_k2_res<<<grid, block, 0, stream>>>(t, w2_0, b2_0, bufA, nullptr, x1, 1);

    // ---- Level 1 (d=2)
    conv_k2_elu<<<grid, block, 0, stream>>>(x1, W1 + 0 * Wsz, B1 + 0 * 128, t, 128, 2);
    conv_k2_res<<<grid, block, 0, stream>>>(t,  W2 + 0 * Wsz, B2 + 0 * 128, x1, nullptr, bufA, 2);

    // ---- Level 2 (d=4)
    conv_k2_elu<<<grid, block, 0, stream>>>(bufA, W1 + 1 * Wsz, B1 + 1 * 128, t, 128, 4);
    conv_k2_res<<<grid, block, 0, stream>>>(t,    W2 + 1 * Wsz, B2 + 1 * 128, bufA, nullptr, out, 4);

    // ---- Level 3 (d=8)
    conv_k2_elu<<<grid, block, 0, stream>>>(out, W1 + 2 * Wsz, B1 + 2 * 128, t, 128, 8);
    conv_k2_res<<<grid, block, 0, stream>>>(t,   W2 + 2 * Wsz, B2 + 2 * 128, out, nullptr, bufA, 8);

    // ---- Level 4 (d=16) + final skip (level-0 output)
    conv_k2_elu<<<grid, block, 0, stream>>>(bufA, W1 + 3 * Wsz, B1 + 3 * 128, t, 128, 16);
    conv_k2_res<<<grid, block, 0, stream>>>(t,    W2 + 3 * Wsz, B2 + 3 * 128, bufA, x1, out, 16);
}

// Round 2
// 381.123 us; speedup vs baseline: 2.3784x; 2.3784x over previous
//
#include <hip/hip_runtime.h>
#include <hip/hip_bf16.h>
#include <math.h>

// TCN via bf16 MFMA (mfma_f32_16x16x32_bf16), channel-last activations.
// B=16, S=4096, C=128, K=2, dilations 1,2,4,8,16. Final = level4 + level0 out.

typedef __attribute__((ext_vector_type(8))) short short8;
typedef __attribute__((ext_vector_type(4))) float floatx4;

#define S_LEN 4096
#define CO 128

__device__ __forceinline__ float elu_f(float v) {
    return v > 0.0f ? v : (__expf(v) - 1.0f);
}

// ---------------------------------------------------------------------------
// conv as GEMM: out[s,co] = sum_ci W0[co,ci]*x[s-d,ci] + W1[co,ci]*x[s,ci]
// x channel-last bf16 [B,S,CIN]; out channel-last bf16 [B,S,128].
// MODE 0: out = elu(conv+b)
// MODE 1: out = conv+b              (1x1 downsample, TAPS=1)
// MODE 2: out = elu(elu(conv+b)+res) [+ skip]
// Block 256 (4 waves): tile 128s x 128co; wave w -> co in [w*32, w*32+32).
// ---------------------------------------------------------------------------
template<int CIN, int TAPS, int MODE>
__global__ __launch_bounds__(256)
void conv_mfma(const __hip_bfloat16* __restrict__ x,
               const short* __restrict__ w0,          // bf16 bits [128][CIN], tap at s-d
               const short* __restrict__ w1,          // bf16 bits [128][CIN], tap at s
               const float* __restrict__ bias,
               const __hip_bfloat16* __restrict__ res,
               const __hip_bfloat16* __restrict__ skip,
               __hip_bfloat16* __restrict__ out,
               int d)
{
    constexpr int KCH = CIN / 32;
    constexpr int STR = CIN + 8;          // +8 bf16 pad -> 2-way (free) LDS banking
    __shared__ short Xls[144 * STR];

    const int tid  = threadIdx.x;
    const int wave = tid >> 6;
    const int lane = tid & 63;
    const int l16  = lane & 15;
    const int quad = lane >> 4;
    const int s0   = blockIdx.x * 128;
    const int b    = blockIdx.y;

    // ---- stage X tile rows [s0-d .. s0+127] (left halo), 16B per thread-iter
    const int rows  = 128 + d;
    const int total = rows * CIN;
    for (int e = tid * 8; e < total; e += 2048) {
        const int r  = e / CIN;
        const int c  = e & (CIN - 1);
        const int gs = s0 - d + r;
        short8 v = {0, 0, 0, 0, 0, 0, 0, 0};
        if (gs >= 0)
            v = *(const short8*)((const short*)x + ((size_t)(b * S_LEN + gs)) * CIN + c);
        *(short8*)(&Xls[r * STR + c]) = v;
    }

    // ---- W fragments (B operand): B[k=ci][n=co]; lane: n=co=wave*32+nb*16+l16,
    // k = kc*32 + quad*8 + j  -> contiguous 8 bf16 in [co][ci] layout.
    short8 wfA[2][KCH], wfB[2][KCH];
    #pragma unroll
    for (int nb = 0; nb < 2; ++nb) {
        const int co = wave * 32 + nb * 16 + l16;
        #pragma unroll
        for (int kc = 0; kc < KCH; ++kc) {
            wfB[nb][kc] = *(const short8*)(w1 + co * CIN + kc * 32 + quad * 8);
            if (TAPS == 2)
                wfA[nb][kc] = *(const short8*)(w0 + co * CIN + kc * 32 + quad * 8);
        }
    }
    __syncthreads();

    floatx4 acc[8][2];
    #pragma unroll
    for (int mb = 0; mb < 8; ++mb) {
        acc[mb][0] = {0.f, 0.f, 0.f, 0.f};
        acc[mb][1] = {0.f, 0.f, 0.f, 0.f};
    }

    // ---- MFMA main: A (x) frag: m = s = mb*16 + l16, k = kc*32 + quad*8 + j
    #pragma unroll
    for (int kc = 0; kc < KCH; ++kc) {
        #pragma unroll
        for (int mb = 0; mb < 8; ++mb) {
            const int colo = kc * 32 + quad * 8;
            const short8 a1 = *(const short8*)(&Xls[(mb * 16 + l16 + d) * STR + colo]);
            short8 a0 = {0, 0, 0, 0, 0, 0, 0, 0};
            if (TAPS == 2)
                a0 = *(const short8*)(&Xls[(mb * 16 + l16) * STR + colo]);
            #pragma unroll
            for (int nb = 0; nb < 2; ++nb) {
                if (TAPS == 2)
                    acc[mb][nb] = __builtin_amdgcn_mfma_f32_16x16x32_bf16(
                        a0, wfA[nb][kc], acc[mb][nb], 0, 0, 0);
                acc[mb][nb] = __builtin_amdgcn_mfma_f32_16x16x32_bf16(
                    a1, wfB[nb][kc], acc[mb][nb], 0, 0, 0);
            }
        }
    }

    // ---- epilogue: D layout col(co)=l16, row(s)=quad*4+r
    const bool has_skip = (skip != nullptr);
    #pragma unroll
    for (int nb = 0; nb < 2; ++nb) {
        const int co = wave * 32 + nb * 16 + l16;
        const float bb = bias[co];
        #pragma unroll
        for (int mb = 0; mb < 8; ++mb) {
            #pragma unroll
            for (int r = 0; r < 4; ++r) {
                const int s = s0 + mb * 16 + quad * 4 + r;
                const size_t o = ((size_t)(b * S_LEN + s)) * CO + co;
                float y = acc[mb][nb][r] + bb;
                if (MODE == 0) y = elu_f(y);
                if (MODE == 2) {
                    y = elu_f(y);
                    y = elu_f(y + __bfloat162float(res[o]));
                    if (has_skip) y += __bfloat162float(skip[o]);
                }
                out[o] = __float2bfloat16(y);
            }
        }
    }
}

// ---------------------------------------------------------------------------
// x_in fp32 [16,64,4096] (channel-first) -> xb bf16 [16,4096,64] (channel-last)
// ---------------------------------------------------------------------------
__global__ __launch_bounds__(256)
void convert_x(const float* __restrict__ in, __hip_bfloat16* __restrict__ outb)
{
    __shared__ float T[64][65];
    const int tid = threadIdx.x;
    const int lane64 = tid & 63;
    const int cg = tid >> 6;            // 0..3
    const int s0 = blockIdx.x * 64;
    const int b  = blockIdx.y;
    #pragma unroll
    for (int j = 0; j < 16; ++j) {
        const int c = cg * 16 + j;
        T[c][lane64] = in[((size_t)(b * 64 + c)) * S_LEN + s0 + lane64];
    }
    __syncthreads();
    #pragma unroll
    for (int j = 0; j < 16; ++j) {
        const int s = cg * 16 + j;
        outb[((size_t)(b * S_LEN + s0 + s)) * 64 + lane64] = __float2bfloat16(T[lane64][s]);
    }
}

// ---------------------------------------------------------------------------
// final bf16 [16,4096,128] channel-last -> d_out fp32 [16,128,4096]
// ---------------------------------------------------------------------------
__global__ __launch_bounds__(256)
void transpose_out(const __hip_bfloat16* __restrict__ in, float* __restrict__ outf)
{
    __shared__ float T[32][130];
    const int tid = threadIdx.x;
    const int s0 = blockIdx.x * 32;
    const int b  = blockIdx.y;
    {
        const int lane64 = tid & 63;
        const int rg = tid >> 6;        // 0..3
        #pragma unroll
        for (int j = 0; j < 8; ++j) {
            const int s = rg * 8 + j;
            const __hip_bfloat16* p = in + ((size_t)(b * S_LEN + s0 + s)) * CO + lane64 * 2;
            T[s][lane64 * 2]     = __bfloat162float(p[0]);
            T[s][lane64 * 2 + 1] = __bfloat162float(p[1]);
        }
    }
    __syncthreads();
    {
        const int lane32 = tid & 31;
        const int cg = tid >> 5;        // 0..7
        #pragma unroll
        for (int j = 0; j < 16; ++j) {
            const int c = cg * 16 + j;
            outf[((size_t)(b * CO + c)) * S_LEN + s0 + lane32] = T[lane32][c];
        }
    }
}

// ---------------------------------------------------------------------------
// weights fp32 [co][ci][k] -> bf16 tap matrices [co][ci] in wq
// ---------------------------------------------------------------------------
#define OFF_L0C1_0 0
#define OFF_L0C1_1 8192
#define OFF_L0C2_0 16384
#define OFF_L0C2_1 32768
#define OFF_DS     49152
#define OFF_C1B    57344     // + li*32768 ; tap1 at +16384
#define OFF_C2B    188416    // + li*32768 ; tap1 at +16384
#define WQ_TOTAL   319488

__device__ __forceinline__ short f2bs(float v) {
    __hip_bfloat16 h = __float2bfloat16(v);
    return *(short*)&h;
}

__global__ __launch_bounds__(256)
void prep_w(const float* __restrict__ w1_0, const float* __restrict__ w2_0,
            const float* __restrict__ ds_w, const float* __restrict__ W1,
            const float* __restrict__ W2, short* __restrict__ wq)
{
    int idx = blockIdx.x * 256 + threadIdx.x;
    const int n_c1 = 128 * 64;    // 8192
    const int n_c2 = 128 * 128;   // 16384
    if (idx < n_c1) {
        wq[OFF_L0C1_0 + idx] = f2bs(w1_0[idx * 2]);
        wq[OFF_L0C1_1 + idx] = f2bs(w1_0[idx * 2 + 1]);
        return;
    }
    idx -= n_c1;
    if (idx < n_c2) {
        wq[OFF_L0C2_0 + idx] = f2bs(w2_0[idx * 2]);
        wq[OFF_L0C2_1 + idx] = f2bs(w2_0[idx * 2 + 1]);
        return;
    }
    idx -= n_c2;
    if (idx < 4 * n_c2) {
        const int li = idx / n_c2, j = idx - li * n_c2;
        wq[OFF_C1B + li * 32768 + j]         = f2bs(W1[(li * n_c2 + j) * 2]);
        wq[OFF_C1B + li * 32768 + 16384 + j] = f2bs(W1[(li * n_c2 + j) * 2 + 1]);
        return;
    }
    idx -= 4 * n_c2;
    if (idx < 4 * n_c2) {
        const int li = idx / n_c2, j = idx - li * n_c2;
        wq[OFF_C2B + li * 32768 + j]         = f2bs(W2[(li * n_c2 + j) * 2]);
        wq[OFF_C2B + li * 32768 + 16384 + j] = f2bs(W2[(li * n_c2 + j) * 2 + 1]);
        return;
    }
    idx -= 4 * n_c2;
    if (idx < n_c1) wq[OFF_DS + idx] = f2bs(ds_w[idx]);
}

// ---------------------------------------------------------------------------
extern "C" void kernel_launch(void* const* d_in, const int* in_sizes, int n_in,
                              void* d_out, int out_size, void* d_ws, size_t ws_size,
                              hipStream_t stream) {
    const float* x_in = (const float*)d_in[0];
    const float* w1_0 = (const float*)d_in[1];
    const float* b1_0 = (const float*)d_in[2];
    const float* w2_0 = (const float*)d_in[3];
    const float* b2_0 = (const float*)d_in[4];
    const float* ds_w = (const float*)d_in[5];
    const float* ds_b = (const float*)d_in[6];
    const float* W1   = (const float*)d_in[7];
    const float* B1   = (const float*)d_in[8];
    const float* W2   = (const float*)d_in[9];
    const float* B2   = (const float*)d_in[10];
    float* out = (float*)d_out;

    char* ws = (char*)d_ws;
    __hip_bfloat16* xb = (__hip_bfloat16*)ws;                    // 8 MB  [16,4096,64]
    __hip_bfloat16* t  = (__hip_bfloat16*)(ws + 8388608ull);     // 16 MB [16,4096,128]
    __hip_bfloat16* x1 = (__hip_bfloat16*)(ws + 25165824ull);    // 16 MB
    __hip_bfloat16* pA = (__hip_bfloat16*)(ws + 41943040ull);    // 16 MB
    __hip_bfloat16* pB = (__hip_bfloat16*)(ws + 58720256ull);    // 16 MB
    short* wq          = (short*)(ws + 75497472ull);             // 624 KB

    dim3 cgrid(32, 16);   // 128-s tiles x batch

    prep_w<<<dim3(640), 256, 0, stream>>>(w1_0, w2_0, ds_w, W1, W2, wq);
    convert_x<<<dim3(64, 16), 256, 0, stream>>>(x_in, xb);

    // ---- Level 0 (d=1, 64->128, downsample residual)
    conv_mfma<64, 2, 0><<<cgrid, 256, 0, stream>>>(xb, wq + OFF_L0C1_0, wq + OFF_L0C1_1,
                                                   b1_0, nullptr, nullptr, t, 1);
    conv_mfma<64, 1, 1><<<cgrid, 256, 0, stream>>>(xb, nullptr, wq + OFF_DS,
                                                   ds_b, nullptr, nullptr, pA, 0);
    conv_mfma<128, 2, 2><<<cgrid, 256, 0, stream>>>(t, wq + OFF_L0C2_0, wq + OFF_L0C2_1,
                                                    b2_0, pA, nullptr, x1, 1);

    // ---- Level 1 (d=2)
    conv_mfma<128, 2, 0><<<cgrid, 256, 0, stream>>>(x1, wq + OFF_C1B, wq + OFF_C1B + 16384,
                                                    B1 + 0, nullptr, nullptr, t, 2);
    conv_mfma<128, 2, 2><<<cgrid, 256, 0, stream>>>(t, wq + OFF_C2B, wq + OFF_C2B + 16384,
                                                    B2 + 0, x1, nullptr, pA, 2);
    // ---- Level 2 (d=4)
    conv_mfma<128, 2, 0><<<cgrid, 256, 0, stream>>>(pA, wq + OFF_C1B + 32768, wq + OFF_C1B + 49152,
                                                    B1 + 128, nullptr, nullptr, t, 4);
    conv_mfma<128, 2, 2><<<cgrid, 256, 0, stream>>>(t, wq + OFF_C2B + 32768, wq + OFF_C2B + 49152,
                                                    B2 + 128, pA, nullptr, pB, 4);
    // ---- Level 3 (d=8)
    conv_mfma<128, 2, 0><<<cgrid, 256, 0, stream>>>(pB, wq + OFF_C1B + 65536, wq + OFF_C1B + 81920,
                                                    B1 + 256, nullptr, nullptr, t, 8);
    conv_mfma<128, 2, 2><<<cgrid, 256, 0, stream>>>(t, wq + OFF_C2B + 65536, wq + OFF_C2B + 81920,
                                                    B2 + 256, pB, nullptr, pA, 8);
    // ---- Level 4 (d=16) + skip (level-0 out)
    conv_mfma<128, 2, 0><<<cgrid, 256, 0, stream>>>(pA, wq + OFF_C1B + 98304, wq + OFF_C1B + 114688,
                                                    B1 + 384, nullptr, nullptr, t, 16);
    conv_mfma<128, 2, 2><<<cgrid, 256, 0, stream>>>(t, wq + OFF_C2B + 98304, wq + OFF_C2B + 114688,
                                                    B2 + 384, pA, x1, pB, 16);

    transpose_out<<<dim3(128, 16), 256, 0, stream>>>(pB, out);
}

// Round 3
// 298.455 us; speedup vs baseline: 3.0372x; 1.2770x over previous
//
#include <hip/hip_runtime.h>
#include <hip/hip_bf16.h>
#include <math.h>

// Fully-fused TCN: one kernel computes all 5 levels (10 dilated convs + 1x1 ds)
// for a 128-sample output chunk, keeping ALL intermediates in LDS.
// Halo: sum of dilations = 62 <= 64 -> fixed 192-row window per block.
// Grid (32 s-chunks, 16 batch) x 512 threads (8 waves), 1 block/CU (LDS-capped).

typedef __attribute__((ext_vector_type(8))) short short8;
typedef __attribute__((ext_vector_type(4))) float floatx4;

#define S_LEN 4096
#define XSTRIDE 72            // 64 ch + 8 pad (bf16 elems)
#define STRIDE 136            // 128 ch + 8 pad
#define XOFF 0                // X: 192 x 72   (dead after phase 2)
#define DOFF 0                // D: 192 x 136  (overlaps X; first written later)
#define TOFF 26112            // T: 192 x 136
#define COFF 52224            // C (= x1): 192 x 136, lives to the end
#define LDS_ELEMS 78336
#define LDS_BYTES 156672

// weight bank offsets (bf16-bit shorts), same layout as prep_w below
#define OFF_L0C1_0 0
#define OFF_L0C1_1 8192
#define OFF_L0C2_0 16384
#define OFF_L0C2_1 32768
#define OFF_DS     49152
#define OFF_C1B    57344      // + lvl*32768 ; tap1 at +16384
#define OFF_C2B    188416     // + lvl*32768 ; tap1 at +16384

__device__ __forceinline__ float elu_f(float v) {
    return v > 0.0f ? v : (__expf(v) - 1.0f);
}
__device__ __forceinline__ short f2bs(float v) {
    __hip_bfloat16 h = __float2bfloat16(v);
    return *reinterpret_cast<short*>(&h);
}
__device__ __forceinline__ float bs2f(short s) {
    __hip_bfloat16 h = *reinterpret_cast<__hip_bfloat16*>(&s);
    return __bfloat162float(h);
}

// ---------------------------------------------------------------------------
// One conv as MFMA: acc[mb][nb] over 3 m-tiles (48 rows) x 4 n-tiles (64 co).
// A from LDS (rows r-d, r), B from global weight bank.
// ---------------------------------------------------------------------------
template<int KCH, int TAPS, int INSTRIDE>
__device__ __forceinline__ void conv_core(
    const short* __restrict__ Lin, int d,
    const short* __restrict__ w0, const short* __restrict__ w1,
    int rowbase, int l16, int quad, int coh, floatx4 (&acc)[3][4])
{
    constexpr int CIN = KCH * 32;
    #pragma unroll
    for (int mb = 0; mb < 3; ++mb)
        #pragma unroll
        for (int nb = 0; nb < 4; ++nb) acc[mb][nb] = {0.f, 0.f, 0.f, 0.f};

    #pragma unroll
    for (int kc = 0; kc < KCH; ++kc) {
        short8 bf0[4], bf1[4];
        #pragma unroll
        for (int nb = 0; nb < 4; ++nb) {
            const int co = coh * 64 + nb * 16 + l16;
            bf1[nb] = *(const short8*)(w1 + co * CIN + kc * 32 + quad * 8);
            if (TAPS == 2)
                bf0[nb] = *(const short8*)(w0 + co * CIN + kc * 32 + quad * 8);
        }
        #pragma unroll
        for (int mb = 0; mb < 3; ++mb) {
            const int r   = rowbase + mb * 16 + l16;
            const int col = kc * 32 + quad * 8;
            const short8 a1 = *(const short8*)(Lin + r * INSTRIDE + col);
            short8 a0 = a1;
            if (TAPS == 2) {
                int r0 = r - d; if (r0 < 0) r0 = 0;   // clamped rows -> garbage, never read
                a0 = *(const short8*)(Lin + r0 * INSTRIDE + col);
            }
            #pragma unroll
            for (int nb = 0; nb < 4; ++nb) {
                if (TAPS == 2)
                    acc[mb][nb] = __builtin_amdgcn_mfma_f32_16x16x32_bf16(a0, bf0[nb], acc[mb][nb], 0, 0, 0);
                acc[mb][nb] = __builtin_amdgcn_mfma_f32_16x16x32_bf16(a1, bf1[nb], acc[mb][nb], 0, 0, 0);
            }
        }
    }
}

// epilogues: D layout col=l16(co-part), row=quad*4+rr
__device__ __forceinline__ void store_elu(short* L, int dstoff, const floatx4 (&acc)[3][4],
    const float* __restrict__ bias, int s0, int rowbase, int l16, int quad, int coh)
{
    #pragma unroll
    for (int nb = 0; nb < 4; ++nb) {
        const int co = coh * 64 + nb * 16 + l16;
        const float bb = bias[co];
        #pragma unroll
        for (int mb = 0; mb < 3; ++mb)
            #pragma unroll
            for (int rr = 0; rr < 4; ++rr) {
                const int row = rowbase + mb * 16 + quad * 4 + rr;
                float y = elu_f(acc[mb][nb][rr] + bb);
                if (s0 + row < 64) y = 0.f;           // s = s0-64+row < 0 -> zero pad
                L[dstoff + row * STRIDE + co] = f2bs(y);
            }
    }
}

__device__ __forceinline__ void store_bias(short* L, int dstoff, const floatx4 (&acc)[3][4],
    const float* __restrict__ bias, int s0, int rowbase, int l16, int quad, int coh)
{
    #pragma unroll
    for (int nb = 0; nb < 4; ++nb) {
        const int co = coh * 64 + nb * 16 + l16;
        const float bb = bias[co];
        #pragma unroll
        for (int mb = 0; mb < 3; ++mb)
            #pragma unroll
            for (int rr = 0; rr < 4; ++rr) {
                const int row = rowbase + mb * 16 + quad * 4 + rr;
                float y = acc[mb][nb][rr] + bb;
                if (s0 + row < 64) y = 0.f;
                L[dstoff + row * STRIDE + co] = f2bs(y);
            }
    }
}

__device__ __forceinline__ void store_res(short* L, int dstoff, int resoff, const floatx4 (&acc)[3][4],
    const float* __restrict__ bias, int s0, int rowbase, int l16, int quad, int coh)
{
    #pragma unroll
    for (int nb = 0; nb < 4; ++nb) {
        const int co = coh * 64 + nb * 16 + l16;
        const float bb = bias[co];
        #pragma unroll
        for (int mb = 0; mb < 3; ++mb)
            #pragma unroll
            for (int rr = 0; rr < 4; ++rr) {
                const int row = rowbase + mb * 16 + quad * 4 + rr;
                float y = elu_f(acc[mb][nb][rr] + bb);
                y = elu_f(y + bs2f(L[resoff + row * STRIDE + co]));
                if (s0 + row < 64) y = 0.f;
                L[dstoff + row * STRIDE + co] = f2bs(y);   // in-place safe: same-elem RAW per thread
            }
    }
}

// ---------------------------------------------------------------------------
__global__ __launch_bounds__(512, 2)
void tcn_fused(const short* __restrict__ xb,   // bf16 bits [16,4096,64] channel-last
               const short* __restrict__ wq,
               const float* __restrict__ b1_0, const float* __restrict__ b2_0,
               const float* __restrict__ ds_b, const float* __restrict__ B1,
               const float* __restrict__ B2, float* __restrict__ out)
{
    extern __shared__ short L[];
    const int tid  = threadIdx.x;
    const int wave = tid >> 6, lane = tid & 63;
    const int l16  = lane & 15, quad = lane >> 4;
    const int mq   = wave & 3,  coh  = wave >> 2;
    const int rowbase = mq * 48;
    const int s0 = blockIdx.x * 128;
    const int b  = blockIdx.y;

    // ---- stage X: rows 0..191 <- xb[b, s0-64+r, :], zero for s<0
    for (int u = tid; u < 1536; u += 512) {
        const int r = u >> 3, c = (u & 7) * 8;
        const int s = s0 - 64 + r;
        short8 v = {0, 0, 0, 0, 0, 0, 0, 0};
        if (s >= 0) v = *(const short8*)(xb + ((size_t)(b * S_LEN + s)) * 64 + c);
        *(short8*)(L + XOFF + r * XSTRIDE + c) = v;
    }
    __syncthreads();

    floatx4 acc[3][4];

    // ---- op1: t1 = elu(conv_d1(X) + b1_0) -> T
    conv_core<2, 2, XSTRIDE>(L + XOFF, 1, wq + OFF_L0C1_0, wq + OFF_L0C1_1,
                             rowbase, l16, quad, coh, acc);
    store_elu(L, TOFF, acc, b1_0, s0, rowbase, l16, quad, coh);
    // ---- ds: C = 1x1(X) + ds_b   (no sync needed: reads X, writes C)
    conv_core<2, 1, XSTRIDE>(L + XOFF, 0, nullptr, wq + OFF_DS,
                             rowbase, l16, quad, coh, acc);
    store_bias(L, COFF, acc, ds_b, s0, rowbase, l16, quad, coh);
    __syncthreads();

    // ---- op2: x1 = elu(elu(conv_d1(T)+b2_0) + C) -> C (in place)
    conv_core<4, 2, STRIDE>(L + TOFF, 1, wq + OFF_L0C2_0, wq + OFF_L0C2_1,
                            rowbase, l16, quad, coh, acc);
    store_res(L, COFF, COFF, acc, b2_0, s0, rowbase, l16, quad, coh);
    __syncthreads();

    // ---- level 1 (d=2): conv1 C->T ; conv2 T,res C -> D
    conv_core<4, 2, STRIDE>(L + COFF, 2, wq + OFF_C1B, wq + OFF_C1B + 16384,
                            rowbase, l16, quad, coh, acc);
    store_elu(L, TOFF, acc, B1 + 0, s0, rowbase, l16, quad, coh);
    __syncthreads();
    conv_core<4, 2, STRIDE>(L + TOFF, 2, wq + OFF_C2B, wq + OFF_C2B + 16384,
                            rowbase, l16, quad, coh, acc);
    store_res(L, DOFF, COFF, acc, B2 + 0, s0, rowbase, l16, quad, coh);
    __syncthreads();

    // ---- level 2 (d=4): D->T ; T,res D -> D
    conv_core<4, 2, STRIDE>(L + DOFF, 4, wq + OFF_C1B + 32768, wq + OFF_C1B + 49152,
                            rowbase, l16, quad, coh, acc);
    store_elu(L, TOFF, acc, B1 + 128, s0, rowbase, l16, quad, coh);
    __syncthreads();
    conv_core<4, 2, STRIDE>(L + TOFF, 4, wq + OFF_C2B + 32768, wq + OFF_C2B + 49152,
                            rowbase, l16, quad, coh, acc);
    store_res(L, DOFF, DOFF, acc, B2 + 128, s0, rowbase, l16, quad, coh);
    __syncthreads();

    // ---- level 3 (d=8)
    conv_core<4, 2, STRIDE>(L + DOFF, 8, wq + OFF_C1B + 65536, wq + OFF_C1B + 81920,
                            rowbase, l16, quad, coh, acc);
    store_elu(L, TOFF, acc, B1 + 256, s0, rowbase, l16, quad, coh);
    __syncthreads();
    conv_core<4, 2, STRIDE>(L + TOFF, 8, wq + OFF_C2B + 65536, wq + OFF_C2B + 81920,
                            rowbase, l16, quad, coh, acc);
    store_res(L, DOFF, DOFF, acc, B2 + 256, s0, rowbase, l16, quad, coh);
    __syncthreads();

    // ---- level 4 (d=16): conv1 D->T
    conv_core<4, 2, STRIDE>(L + DOFF, 16, wq + OFF_C1B + 98304, wq + OFF_C1B + 114688,
                            rowbase, l16, quad, coh, acc);
    store_elu(L, TOFF, acc, B1 + 384, s0, rowbase, l16, quad, coh);
    __syncthreads();
    // ---- final: out = elu(elu(conv_d16(T)+B2[4]) + D) + C  -> global fp32 NCH
    conv_core<4, 2, STRIDE>(L + TOFF, 16, wq + OFF_C2B + 98304, wq + OFF_C2B + 114688,
                            rowbase, l16, quad, coh, acc);
    #pragma unroll
    for (int nb = 0; nb < 4; ++nb) {
        const int co = coh * 64 + nb * 16 + l16;
        const float bb = B2[384 + co];
        #pragma unroll
        for (int mb = 0; mb < 3; ++mb) {
            const int row0 = rowbase + mb * 16 + quad * 4;
            if (row0 < 64) continue;                  // halo rows: no output
            floatx4 y4;
            #pragma unroll
            for (int rr = 0; rr < 4; ++rr) {
                const int row = row0 + rr;
                float y = elu_f(acc[mb][nb][rr] + bb);
                y = elu_f(y + bs2f(L[DOFF + row * STRIDE + co]));
                y += bs2f(L[COFF + row * STRIDE + co]);   // final skip = x1
                y4[rr] = y;
            }
            *(floatx4*)(out + ((size_t)(b * 128 + co)) * S_LEN + s0 + row0 - 64) = y4;
        }
    }
}

// ---------------------------------------------------------------------------
// x_in fp32 [16,64,4096] -> xb bf16 [16,4096,64] channel-last
// ---------------------------------------------------------------------------
__global__ __launch_bounds__(256)
void convert_x(const float* __restrict__ in, __hip_bfloat16* __restrict__ outb)
{
    __shared__ float T[64][65];
    const int tid = threadIdx.x;
    const int lane64 = tid & 63;
    const int cg = tid >> 6;
    const int s0 = blockIdx.x * 64;
    const int b  = blockIdx.y;
    #pragma unroll
    for (int j = 0; j < 16; ++j) {
        const int c = cg * 16 + j;
        T[c][lane64] = in[((size_t)(b * 64 + c)) * S_LEN + s0 + lane64];
    }
    __syncthreads();
    #pragma unroll
    for (int j = 0; j < 16; ++j) {
        const int s = cg * 16 + j;
        outb[((size_t)(b * S_LEN + s0 + s)) * 64 + lane64] = __float2bfloat16(T[lane64][s]);
    }
}

// ---------------------------------------------------------------------------
// weights fp32 [co][ci][k] -> bf16 tap matrices [co][ci]
// ---------------------------------------------------------------------------
__global__ __launch_bounds__(256)
void prep_w(const float* __restrict__ w1_0, const float* __restrict__ w2_0,
            const float* __restrict__ ds_w, const float* __restrict__ W1,
            const float* __restrict__ W2, short* __restrict__ wq)
{
    int idx = blockIdx.x * 256 + threadIdx.x;
    const int n_c1 = 128 * 64;
    const int n_c2 = 128 * 128;
    if (idx < n_c1) {
        wq[OFF_L0C1_0 + idx] = f2bs(w1_0[idx * 2]);
        wq[OFF_L0C1_1 + idx] = f2bs(w1_0[idx * 2 + 1]);
        return;
    }
    idx -= n_c1;
    if (idx < n_c2) {
        wq[OFF_L0C2_0 + idx] = f2bs(w2_0[idx * 2]);
        wq[OFF_L0C2_1 + idx] = f2bs(w2_0[idx * 2 + 1]);
        return;
    }
    idx -= n_c2;
    if (idx < 4 * n_c2) {
        const int li = idx / n_c2, j = idx - li * n_c2;
        wq[OFF_C1B + li * 32768 + j]         = f2bs(W1[(li * n_c2 + j) * 2]);
        wq[OFF_C1B + li * 32768 + 16384 + j] = f2bs(W1[(li * n_c2 + j) * 2 + 1]);
        return;
    }
    idx -= 4 * n_c2;
    if (idx < 4 * n_c2) {
        const int li = idx / n_c2, j = idx - li * n_c2;
        wq[OFF_C2B + li * 32768 + j]         = f2bs(W2[(li * n_c2 + j) * 2]);
        wq[OFF_C2B + li * 32768 + 16384 + j] = f2bs(W2[(li * n_c2 + j) * 2 + 1]);
        return;
    }
    idx -= 4 * n_c2;
    if (idx < n_c1) wq[OFF_DS + idx] = f2bs(ds_w[idx]);
}

// ---------------------------------------------------------------------------
extern "C" void kernel_launch(void* const* d_in, const int* in_sizes, int n_in,
                              void* d_out, int out_size, void* d_ws, size_t ws_size,
                              hipStream_t stream) {
    const float* x_in = (const float*)d_in[0];
    const float* w1_0 = (const float*)d_in[1];
    const float* b1_0 = (const float*)d_in[2];
    const float* w2_0 = (const float*)d_in[3];
    const float* b2_0 = (const float*)d_in[4];
    const float* ds_w = (const float*)d_in[5];
    const float* ds_b = (const float*)d_in[6];
    const float* W1   = (const float*)d_in[7];
    const float* B1   = (const float*)d_in[8];
    const float* W2   = (const float*)d_in[9];
    const float* B2   = (const float*)d_in[10];
    float* out = (float*)d_out;

    char* ws = (char*)d_ws;
    __hip_bfloat16* xb = (__hip_bfloat16*)ws;            // 8 MB [16,4096,64]
    short* wq          = (short*)(ws + 8388608ull);      // 624 KB weight bank

    // allow >64KB dynamic LDS (idempotent; host-side, capture-safe)
    (void)hipFuncSetAttribute((const void*)tcn_fused,
                              hipFuncAttributeMaxDynamicSharedMemorySize, LDS_BYTES);

    prep_w<<<dim3(640), 256, 0, stream>>>(w1_0, w2_0, ds_w, W1, W2, wq);
    convert_x<<<dim3(64, 16), 256, 0, stream>>>(x_in, xb);
    tcn_fused<<<dim3(32, 16), dim3(512), LDS_BYTES, stream>>>(
        (const short*)xb, wq, b1_0, b2_0, ds_b, B1, B2, out);
}